// Round 1
// baseline (6594.923 us; speedup 1.0000x reference)
//
#include <hip/hip_runtime.h>
#include <math.h>

#define DH 100      // hidden dim
#define PPB 32      // points per batch
#define NBATCH 4    // 4*32 = 128 slots, 101 real steps, rest padded with ccw=0
#define APAD 104    // LDS row stride (floats), 16B-aligned

// ws float offsets
#define WS_CCW   0     // [0,128)   quadrature weights, 0-padded
#define WS_XSC   128   // [128,256) (steps+1)*0.5 per step, 0-padded
#define WS_OH0   256   // [256,259) oh[:,0] per k
#define WS_EOH1  260   // [260,263) exp(oh[:,1]) per k
#define WS_X2    272   // [272,272+N) x2 = mono(0, x1, 0)

__global__ void setup_kernel(const float* __restrict__ logits,
                             const float* __restrict__ hb0,
                             const float* __restrict__ hW1,
                             const float* __restrict__ hb1,
                             const float* __restrict__ hW2,
                             const float* __restrict__ hb2,
                             const float* __restrict__ hW3,
                             const float* __restrict__ hb3,
                             float* __restrict__ ws,
                             float* __restrict__ out2, int n)
{
    int t = threadIdx.x;
    // third output = logits passthrough (all blocks help)
    for (int i = blockIdx.x * blockDim.x + t; i < n; i += gridDim.x * blockDim.x)
        out2[i] = logits[i];
    if (blockIdx.x != 0) return;

    // Clenshaw-Curtis quadrature in fp64 (matches numpy fp64 -> f32 cast)
    if (t < 128) {
        double ccw = 0.0, xs = 0.0;
        if (t <= 100) {
            double s = (double)t;
            for (int j = 0; j <= 100; j += 2) {
                double wj = (j == 0) ? 1.0 : 2.0 / (1.0 - (double)j * (double)j);
                double lam;
                if (t == 0) lam = 0.5;
                else {
                    lam = cos((double)j * s * M_PI / 100.0);
                    if (t == 100) lam *= 0.5;
                }
                ccw += lam * 0.02 * wj;
            }
            xs = (cos(s * M_PI / 100.0) + 1.0) * 0.5;
        }
        ws[WS_CCW + t] = (float)ccw;
        ws[WS_XSC + t] = (float)xs;
    }
    __syncthreads();

    // h-MLP at h=0: layer0 output is relu(hb0). Result is a per-k constant.
    __shared__ float bufA[DH], bufB[DH];
    for (int k = 0; k < 3; ++k) {
        if (t < DH) bufA[t] = fmaxf(hb0[k * DH + t], 0.f);
        __syncthreads();
        if (t < DH) {
            float acc = hb1[k * DH + t];
            const float* w = hW1 + (size_t)(k * DH + t) * DH;
            for (int i = 0; i < DH; ++i) acc = fmaf(w[i], bufA[i], acc);
            bufB[t] = fmaxf(acc, 0.f);
        }
        __syncthreads();
        if (t < DH) {
            float acc = hb2[k * DH + t];
            const float* w = hW2 + (size_t)(k * DH + t) * DH;
            for (int i = 0; i < DH; ++i) acc = fmaf(w[i], bufB[i], acc);
            bufA[t] = fmaxf(acc, 0.f);
        }
        __syncthreads();
        if (t < 2) {
            float acc = hb3[k * 2 + t];
            const float* w = hW3 + (size_t)(k * 2 + t) * DH;
            for (int i = 0; i < DH; ++i) acc = fmaf(w[i], bufA[i], acc);
            if (t == 0) ws[WS_OH0 + k] = acc;
            else        ws[WS_EOH1 + k] = expf(acc);
        }
        __syncthreads();
    }
}

// One block per (sample, k). 128 threads: thread = output neuron (100 active).
// 32 points in flight (acc[32] in VGPRs), activations via LDS broadcast.
__global__ __launch_bounds__(128)
void mono_kernel(const float* __restrict__ xsrc,
                 const float* __restrict__ iW0, const float* __restrict__ ib0,
                 const float* __restrict__ iW1, const float* __restrict__ ib1,
                 const float* __restrict__ iW2, const float* __restrict__ ib2,
                 const float* __restrict__ iW3, const float* __restrict__ ib3,
                 const float* __restrict__ ws,
                 float* __restrict__ dst0,   // for k = kbase   (blockIdx.y==0)
                 float* __restrict__ dst1,   // for k = kbase+1 (blockIdx.y==1)
                 int kbase)
{
    int n = blockIdx.x;
    int k = kbase + blockIdx.y;
    float* dst = (blockIdx.y == 0) ? dst0 : dst1;
    int t = threadIdx.x;
    float x = xsrc[n];

    __shared__ __align__(16) float A1[PPB][APAD];
    __shared__ __align__(16) float A2[PPB][APAD];

    const float* W1k = iW1 + (size_t)k * DH * DH;
    const float* W2k = iW2 + (size_t)k * DH * DH;

    float w0t = 0.f, b0t = 0.f, b1t = 0.f, b2t = 0.f, w3t = 0.f;
    if (t < DH) {
        w0t = iW0[(k * DH + t) * 3 + 0];  // only feature 0 matters (h == 0)
        b0t = ib0[k * DH + t];
        b1t = ib1[k * DH + t];
        b2t = ib2[k * DH + t];
        w3t = iW3[k * DH + t];
    }
    float b3k = ib3[k];
    float zacc = 0.f;

    for (int b = 0; b < NBATCH; ++b) {
        __syncthreads();  // A1 free from previous batch's reduce
        // stage 1: a1[p][t] = relu(x_s * w0 + b0); pad steps have xsc=0 (finite)
        if (t < DH) {
            #pragma unroll
            for (int p = 0; p < PPB; ++p) {
                float xw = x * ws[WS_XSC + b * PPB + p];
                A1[p][t] = fmaxf(fmaf(xw, w0t, b0t), 0.f);
            }
        }
        __syncthreads();
        // layer 2: 100x100 matvec, 32 points in flight
        if (t < DH) {
            float acc[PPB];
            #pragma unroll
            for (int p = 0; p < PPB; ++p) acc[p] = b1t;
            const float4* wr = (const float4*)(W1k + t * DH);
            for (int i0 = 0; i0 < DH; i0 += 4) {
                float4 w = wr[i0 >> 2];
                #pragma unroll
                for (int p = 0; p < PPB; ++p) {
                    float4 a = *(const float4*)&A1[p][i0];
                    float s0 = fmaf(w.x, a.x, acc[p]);
                    s0 = fmaf(w.y, a.y, s0);
                    s0 = fmaf(w.z, a.z, s0);
                    acc[p] = fmaf(w.w, a.w, s0);
                }
            }
            #pragma unroll
            for (int p = 0; p < PPB; ++p) A2[p][t] = fmaxf(acc[p], 0.f);
        }
        __syncthreads();
        // layer 3 + w3 product (partials into reused A1)
        if (t < DH) {
            float acc[PPB];
            #pragma unroll
            for (int p = 0; p < PPB; ++p) acc[p] = b2t;
            const float4* wr = (const float4*)(W2k + t * DH);
            for (int i0 = 0; i0 < DH; i0 += 4) {
                float4 w = wr[i0 >> 2];
                #pragma unroll
                for (int p = 0; p < PPB; ++p) {
                    float4 a = *(const float4*)&A2[p][i0];
                    float s0 = fmaf(w.x, a.x, acc[p]);
                    s0 = fmaf(w.y, a.y, s0);
                    s0 = fmaf(w.z, a.z, s0);
                    acc[p] = fmaf(w.w, a.w, s0);
                }
            }
            #pragma unroll
            for (int p = 0; p < PPB; ++p)
                A1[p][t] = fmaxf(acc[p], 0.f) * w3t;
        }
        __syncthreads();
        // per-point reduction over neurons; dz = elu(o)+1; quadrature weight
        if (t < PPB) {
            int s = b * PPB + t;
            float4 s4 = make_float4(0.f, 0.f, 0.f, 0.f);
            const float4* pr = (const float4*)&A1[t][0];
            for (int i0 = 0; i0 < DH; i0 += 4) {
                float4 v = pr[i0 >> 2];
                s4.x += v.x; s4.y += v.y; s4.z += v.z; s4.w += v.w;
            }
            float o = b3k + s4.x + s4.y + s4.z + s4.w;
            float dz = (o > 0.f) ? (o + 1.f) : expf(o);  // elu(o) + 1
            zacc += dz * ws[WS_CCW + s];
        }
    }
    // reduce zacc across lanes 0..31 of wave 0 (others hold 0)
    if (t < 64) {
        float zs = zacc;
        zs += __shfl_xor(zs, 16);
        zs += __shfl_xor(zs, 8);
        zs += __shfl_xor(zs, 4);
        zs += __shfl_xor(zs, 2);
        zs += __shfl_xor(zs, 1);
        if (t == 0) {
            float z = 0.5f * x * zs;
            dst[n] = fmaf(ws[WS_EOH1 + k], z, ws[WS_OH0 + k]);
        }
    }
}

extern "C" void kernel_launch(void* const* d_in, const int* in_sizes, int n_in,
                              void* d_out, int out_size, void* d_ws, size_t ws_size,
                              hipStream_t stream)
{
    const float* logits = (const float*)d_in[0];
    const float* iW0 = (const float*)d_in[2];
    const float* ib0 = (const float*)d_in[3];
    const float* iW1 = (const float*)d_in[4];
    const float* ib1 = (const float*)d_in[5];
    const float* iW2 = (const float*)d_in[6];
    const float* ib2 = (const float*)d_in[7];
    const float* iW3 = (const float*)d_in[8];
    const float* ib3 = (const float*)d_in[9];
    const float* hb0 = (const float*)d_in[11];
    const float* hW1 = (const float*)d_in[12];
    const float* hb1 = (const float*)d_in[13];
    const float* hW2 = (const float*)d_in[14];
    const float* hb2 = (const float*)d_in[15];
    const float* hW3 = (const float*)d_in[16];
    const float* hb3 = (const float*)d_in[17];
    float* out = (float*)d_out;
    float* ws = (float*)d_ws;
    int n = in_sizes[0];

    // constants (fp64 quadrature, per-k oh from h=0) + logits passthrough
    hipLaunchKernelGGL(setup_kernel, dim3(64), dim3(256), 0, stream,
                       logits, hb0, hW1, hb1, hW2, hb2, hW3, hb3, ws, out + 2 * n, n);
    // phase A: k=0 -> x2 (workspace), k=1 -> y1 (out[0:N))
    hipLaunchKernelGGL(mono_kernel, dim3(n, 2), dim3(128), 0, stream,
                       logits, iW0, ib0, iW1, ib1, iW2, ib2, iW3, ib3, ws,
                       ws + WS_X2, out, 0);
    // phase B: k=2 on x2 -> y2 (out[N:2N))
    hipLaunchKernelGGL(mono_kernel, dim3(n, 1), dim3(128), 0, stream,
                       ws + WS_X2, iW0, ib0, iW1, ib1, iW2, ib2, iW3, ib3, ws,
                       out + n, out, 2);
}

// Round 2
// 1071.999 us; speedup vs baseline: 6.1520x; 6.1520x over previous
//
#include <hip/hip_runtime.h>
#include <math.h>

typedef short bf16x8 __attribute__((ext_vector_type(8)));
typedef float f32x16 __attribute__((ext_vector_type(16)));

#define DH 100      // hidden dim
#define SPB 20      // samples per block -> 2020 rows, padded to 2048
#define CHROWS 128  // rows per chunk (4 waves x 32)
#define NCH 16      // chunks per block
#define WSTR 136    // LDS row stride in bf16 elems (bank-friendly: 272B)

// ws float offsets
#define WS_CCW   0     // [0,128)   quadrature weights, 0-padded
#define WS_XSC   128   // [128,256) (steps+1)*0.5 per step, 0-padded
#define WS_OH0   256
#define WS_EOH1  260
#define WS_X2    272   // x2 = mono(0, x1, 0)

__device__ __forceinline__ unsigned short f2bf(float f) {
    unsigned int u = __float_as_uint(f);
    unsigned int r = (u + 0x7FFFu + ((u >> 16) & 1u)) >> 16;  // RNE
    return (unsigned short)r;
}

__global__ void setup_kernel(const float* __restrict__ logits,
                             const float* __restrict__ hb0,
                             const float* __restrict__ hW1,
                             const float* __restrict__ hb1,
                             const float* __restrict__ hW2,
                             const float* __restrict__ hb2,
                             const float* __restrict__ hW3,
                             const float* __restrict__ hb3,
                             float* __restrict__ ws,
                             float* __restrict__ out2, int n)
{
    int t = threadIdx.x;
    for (int i = blockIdx.x * blockDim.x + t; i < n; i += gridDim.x * blockDim.x)
        out2[i] = logits[i];
    if (blockIdx.x != 0) return;

    if (t < 128) {
        double ccw = 0.0, xs = 0.0;
        if (t <= 100) {
            double s = (double)t;
            for (int j = 0; j <= 100; j += 2) {
                double wj = (j == 0) ? 1.0 : 2.0 / (1.0 - (double)j * (double)j);
                double lam;
                if (t == 0) lam = 0.5;
                else {
                    lam = cos((double)j * s * M_PI / 100.0);
                    if (t == 100) lam *= 0.5;
                }
                ccw += lam * 0.02 * wj;
            }
            xs = (cos(s * M_PI / 100.0) + 1.0) * 0.5;
        }
        ws[WS_CCW + t] = (float)ccw;
        ws[WS_XSC + t] = (float)xs;
    }
    __syncthreads();

    __shared__ float bufA[DH], bufB[DH];
    for (int k = 0; k < 3; ++k) {
        if (t < DH) bufA[t] = fmaxf(hb0[k * DH + t], 0.f);
        __syncthreads();
        if (t < DH) {
            float acc = hb1[k * DH + t];
            const float* w = hW1 + (size_t)(k * DH + t) * DH;
            for (int i = 0; i < DH; ++i) acc = fmaf(w[i], bufA[i], acc);
            bufB[t] = fmaxf(acc, 0.f);
        }
        __syncthreads();
        if (t < DH) {
            float acc = hb2[k * DH + t];
            const float* w = hW2 + (size_t)(k * DH + t) * DH;
            for (int i = 0; i < DH; ++i) acc = fmaf(w[i], bufB[i], acc);
            bufA[t] = fmaxf(acc, 0.f);
        }
        __syncthreads();
        if (t < 2) {
            float acc = hb3[k * 2 + t];
            const float* w = hW3 + (size_t)(k * 2 + t) * DH;
            for (int i = 0; i < DH; ++i) acc = fmaf(w[i], bufA[i], acc);
            if (t == 0) ws[WS_OH0 + k] = acc;
            else        ws[WS_EOH1 + k] = expf(acc);
        }
        __syncthreads();
    }
}

// One block = 20 samples x 101 points = 2020 rows (pad 2048), 256 thr = 4 waves.
// Fused 3-layer MLP: layer1 rank-1 in registers, layers 2/3 via 32x32x16 bf16
// MFMA with both weight matrices cached as register fragments.
__global__ __launch_bounds__(256, 1)
void mono_mfma(const float* __restrict__ xsrc,
               const float* __restrict__ iW0, const float* __restrict__ ib0,
               const float* __restrict__ iW1, const float* __restrict__ ib1,
               const float* __restrict__ iW2, const float* __restrict__ ib2,
               const float* __restrict__ iW3, const float* __restrict__ ib3,
               const float* __restrict__ ws,
               float* __restrict__ dst0, float* __restrict__ dst1,
               int kbase, int nTot)
{
    __shared__ unsigned short WA[128 * WSTR];   // W staging, then per-chunk A2 + epilogue scratch
    __shared__ unsigned int wb_s[128];          // packed (bf16(b0)<<16)|bf16(w0)
    __shared__ float b1_s[128], b2_s[128], w3_s[128];
    __shared__ float xsc_s[128], ccw_s[128];
    __shared__ float xs_s[32], zs[32];

    const int tid = threadIdx.x;
    const int lane = tid & 63;
    const int wv = tid >> 6;
    const int hf = lane >> 5;
    const int l31 = lane & 31;
    const int k = kbase + blockIdx.y;
    float* __restrict__ dst = (blockIdx.y == 0) ? dst0 : dst1;

    if (tid < 128) {
        xsc_s[tid] = ws[WS_XSC + tid];
        ccw_s[tid] = ws[WS_CCW + tid];
        bool r = tid < DH;
        float w0 = r ? iW0[(k * DH + tid) * 3] : 0.f;   // h==0: only feature 0
        float b0 = r ? ib0[k * DH + tid] : 0.f;
        wb_s[tid] = ((unsigned int)f2bf(b0) << 16) | (unsigned int)f2bf(w0);
        b1_s[tid] = r ? ib1[k * DH + tid] : 0.f;
        b2_s[tid] = r ? ib2[k * DH + tid] : 0.f;
        w3_s[tid] = r ? iW3[k * DH + tid] : 0.f;
    }
    if (tid < 32) {
        int n = blockIdx.x * SPB + tid;
        xs_s[tid] = (tid < SPB && n < nTot) ? xsrc[n] : 0.f;
        zs[tid] = 0.f;
    }

    const float* W1g = iW1 + (size_t)k * DH * DH;
    const float* W2g = iW2 + (size_t)k * DH * DH;

    bf16x8 w1f[4][8], w2f[4][8];

    // stage W1 (fp32->bf16, zero-padded to 128x128), read fragments, repeat for W2
    for (int i = tid; i < 128 * 128; i += 256) {
        int n = i >> 7, kk = i & 127;
        float v = (n < DH && kk < DH) ? W1g[n * DH + kk] : 0.f;
        WA[n * WSTR + kk] = f2bf(v);
    }
    __syncthreads();
    #pragma unroll
    for (int nt = 0; nt < 4; ++nt)
        #pragma unroll
        for (int ks = 0; ks < 8; ++ks)
            w1f[nt][ks] = *(const bf16x8*)&WA[(nt * 32 + l31) * WSTR + ks * 16 + hf * 8];
    __syncthreads();
    for (int i = tid; i < 128 * 128; i += 256) {
        int n = i >> 7, kk = i & 127;
        float v = (n < DH && kk < DH) ? W2g[n * DH + kk] : 0.f;
        WA[n * WSTR + kk] = f2bf(v);
    }
    __syncthreads();
    #pragma unroll
    for (int nt = 0; nt < 4; ++nt)
        #pragma unroll
        for (int ks = 0; ks < 8; ++ks)
            w2f[nt][ks] = *(const bf16x8*)&WA[(nt * 32 + l31) * WSTR + ks * 16 + hf * 8];
    __syncthreads();

    float b1c[4], b2c[4], w3c[4];
    #pragma unroll
    for (int nt = 0; nt < 4; ++nt) {
        b1c[nt] = b1_s[nt * 32 + l31];
        b2c[nt] = b2_s[nt * 32 + l31];
        w3c[nt] = w3_s[nt * 32 + l31];
    }
    const float b3 = ib3[k];
    const float e1 = ws[WS_EOH1 + k];
    const float o0 = ws[WS_OH0 + k];

    for (int ch = 0; ch < NCH; ++ch) {
        const int mrow = ch * CHROWS + wv * 32 + l31;   // row this lane owns
        const int nloc = (mrow * 649) >> 16;            // == mrow / 101 for mrow < 2048
        const int p = mrow - nloc * 101;
        const float u = xs_s[nloc] * xsc_s[p];

        // ---- layer 1 (rank-1, register A-frags) + MFMA layer 2 ----
        f32x16 acc[4];
        #pragma unroll
        for (int nt = 0; nt < 4; ++nt)
            #pragma unroll
            for (int r = 0; r < 16; ++r) acc[nt][r] = b1c[nt];

        #pragma unroll
        for (int ks = 0; ks < 8; ++ks) {
            int k0 = ks * 16 + hf * 8;
            uint4 qa = *(const uint4*)&wb_s[k0];
            uint4 qb = *(const uint4*)&wb_s[k0 + 4];
            unsigned int qs[8] = {qa.x, qa.y, qa.z, qa.w, qb.x, qb.y, qb.z, qb.w};
            union { bf16x8 v; unsigned short u16[8]; } af;
            #pragma unroll
            for (int j = 0; j < 8; ++j) {
                float w0v = __uint_as_float(qs[j] << 16);
                float b0v = __uint_as_float(qs[j] & 0xFFFF0000u);
                af.u16[j] = f2bf(fmaxf(fmaf(u, w0v, b0v), 0.f));
            }
            #pragma unroll
            for (int nt = 0; nt < 4; ++nt)
                acc[nt] = __builtin_amdgcn_mfma_f32_32x32x16_bf16(af.v, w1f[nt][ks], acc[nt], 0, 0, 0);
        }

        // ---- A2 = relu(acc) -> LDS bf16 (wave-exclusive rows, no barrier) ----
        #pragma unroll
        for (int nt = 0; nt < 4; ++nt) {
            int c = nt * 32 + l31;
            #pragma unroll
            for (int r = 0; r < 16; ++r) {
                int rowc = (r & 3) + 8 * (r >> 2) + 4 * hf;
                WA[(wv * 32 + rowc) * WSTR + c] = f2bf(fmaxf(acc[nt][r], 0.f));
            }
        }

        // ---- layer 3 MFMA ----
        f32x16 acc2[4];
        #pragma unroll
        for (int nt = 0; nt < 4; ++nt)
            #pragma unroll
            for (int r = 0; r < 16; ++r) acc2[nt][r] = b2c[nt];
        #pragma unroll
        for (int ks = 0; ks < 8; ++ks) {
            bf16x8 af2 = *(const bf16x8*)&WA[(wv * 32 + l31) * WSTR + ks * 16 + hf * 8];
            #pragma unroll
            for (int nt = 0; nt < 4; ++nt)
                acc2[nt] = __builtin_amdgcn_mfma_f32_32x32x16_bf16(af2, w2f[nt][ks], acc2[nt], 0, 0, 0);
        }

        // ---- epilogue: relu * w3, col-reduce via LDS scratch transpose ----
        #pragma unroll
        for (int r = 0; r < 16; ++r) {
            float t = fmaxf(acc2[0][r], 0.f) * w3c[0];
            t = fmaf(fmaxf(acc2[1][r], 0.f), w3c[1], t);
            t = fmaf(fmaxf(acc2[2][r], 0.f), w3c[2], t);
            t = fmaf(fmaxf(acc2[3][r], 0.f), w3c[3], t);
            int rowc = (r & 3) + 8 * (r >> 2) + 4 * hf;
            float* scr = (float*)((char*)WA + (size_t)(wv * 32 + rowc) * (WSTR * 2));
            scr[l31] = t;   // 32 partial col-sums per row
        }
        if (hf == 0) {
            const float4* pr = (const float4*)((char*)WA + (size_t)(wv * 32 + l31) * (WSTR * 2));
            float s0 = 0.f, s1 = 0.f, s2 = 0.f, s3 = 0.f;
            #pragma unroll
            for (int q = 0; q < 8; ++q) {
                float4 v = pr[q];
                s0 += v.x; s1 += v.y; s2 += v.z; s3 += v.w;
            }
            float o = b3 + ((s0 + s1) + (s2 + s3));
            float dz = (o > 0.f) ? (o + 1.f) : expf(o);   // elu(o) + 1
            atomicAdd(&zs[nloc], dz * ccw_s[p]);
        }
    }

    __syncthreads();
    if (tid < SPB) {
        int n = blockIdx.x * SPB + tid;
        if (n < nTot) dst[n] = fmaf(e1, 0.5f * xs_s[tid] * zs[tid], o0);
    }
}

extern "C" void kernel_launch(void* const* d_in, const int* in_sizes, int n_in,
                              void* d_out, int out_size, void* d_ws, size_t ws_size,
                              hipStream_t stream)
{
    const float* logits = (const float*)d_in[0];
    const float* iW0 = (const float*)d_in[2];
    const float* ib0 = (const float*)d_in[3];
    const float* iW1 = (const float*)d_in[4];
    const float* ib1 = (const float*)d_in[5];
    const float* iW2 = (const float*)d_in[6];
    const float* ib2 = (const float*)d_in[7];
    const float* iW3 = (const float*)d_in[8];
    const float* ib3 = (const float*)d_in[9];
    const float* hb0 = (const float*)d_in[11];
    const float* hW1 = (const float*)d_in[12];
    const float* hb1 = (const float*)d_in[13];
    const float* hW2 = (const float*)d_in[14];
    const float* hb2 = (const float*)d_in[15];
    const float* hW3 = (const float*)d_in[16];
    const float* hb3 = (const float*)d_in[17];
    float* out = (float*)d_out;
    float* ws = (float*)d_ws;
    int n = in_sizes[0];
    int nblocks = (n + SPB - 1) / SPB;

    hipLaunchKernelGGL(setup_kernel, dim3(64), dim3(256), 0, stream,
                       logits, hb0, hW1, hb1, hW2, hb2, hW3, hb3, ws, out + 2 * n, n);
    // phase A: k=0 -> x2 (workspace), k=1 -> y1
    hipLaunchKernelGGL(mono_mfma, dim3(nblocks, 2), dim3(256), 0, stream,
                       logits, iW0, ib0, iW1, ib1, iW2, ib2, iW3, ib3, ws,
                       ws + WS_X2, out, 0, n);
    // phase B: k=2 on x2 -> y2
    hipLaunchKernelGGL(mono_mfma, dim3(nblocks, 1), dim3(256), 0, stream,
                       ws + WS_X2, iW0, ib0, iW1, ib1, iW2, ib2, iW3, ib3, ws,
                       out + n, out + n, 2, n);
}